// Round 6
// baseline (518.414 us; speedup 1.0000x reference)
//
#include <hip/hip_runtime.h>
#include <hip/hip_cooperative_groups.h>

#define D 16
#define NW_MAX 256
#define CHUNK4 2048   // fallback path chunk

namespace cg = cooperative_groups;

// ===========================================================================
// Fused cooperative kernel: zero+hist -> scan+reserve+scatter -> mm -> relu.
// One dispatch. Cross-phase buffers use agent-scoped atomic load/store so the
// non-coherent per-XCD L2s can never serve stale lines:
//   - out zeroing: scoped stores (write-through, no dirty-L2 hazard vs the
//     phase-2 atomics that execute at the coherent point)
//   - perm: scoped stores in phase 1; plain loads in phase 2 are safe because
//     no XCD caches perm lines before the writes complete (grid.sync between)
//   - final relu: scoped loads (bypass any clean-zero lines from phase 0)
// ===========================================================================
__global__ __launch_bounds__(256, 3) void fused_kernel(
    const float* __restrict__ x, const float* __restrict__ W,
    const int* __restrict__ u, const int* __restrict__ v,
    const int* __restrict__ widx, float* __restrict__ out,
    int* __restrict__ bucketTotal, int* __restrict__ gcur,
    unsigned long long* __restrict__ perm64, int E, int ntot) {
    cg::grid_group grid = cg::this_grid();
    __shared__ int sh[NW_MAX];        // chunk hist (persists into phase 1)
    __shared__ int sc[NW_MAX];        // scan scratch
    __shared__ int sbase[NW_MAX + 1]; // bucket bases
    __shared__ int lb[NW_MAX];        // scatter cursors
    int t = threadIdx.x;
    int b = blockIdx.x;
    int G = gridDim.x;

    int chunk = (E + G - 1) / G;      // one chunk per block
    int cbeg = b * chunk;
    int cend = cbeg + chunk; if (cend > E) cend = E;

    // ---- phase 0: zero out (scoped); widx histogram of this block's chunk --
    for (int i = b * 256 + t; i < ntot; i += G * 256)
        __hip_atomic_store(&out[i], 0.0f, __ATOMIC_RELAXED,
                           __HIP_MEMORY_SCOPE_AGENT);
    sh[t] = 0;
    __syncthreads();
    for (int k = cbeg + t; k < cend; k += 256)
        atomicAdd(&sh[widx[k]], 1);
    __syncthreads();
    if (sh[t]) atomicAdd(&bucketTotal[t], sh[t]);
    grid.sync();

    // ---- phase 1: every block scans totals; reserve slots; scatter chunk ---
    int mine = __hip_atomic_load(&bucketTotal[t], __ATOMIC_RELAXED,
                                 __HIP_MEMORY_SCOPE_AGENT);
    sc[t] = mine;
    __syncthreads();
    for (int d = 1; d < NW_MAX; d <<= 1) {
        int val = sc[t];
        int add = (t >= d) ? sc[t - d] : 0;
        __syncthreads();
        sc[t] = val + add;
        __syncthreads();
    }
    sbase[t] = sc[t] - mine;
    if (t == NW_MAX - 1) sbase[NW_MAX] = sc[t];
    __syncthreads();
    lb[t] = sbase[t] + (sh[t] ? atomicAdd(&gcur[t], sh[t]) : 0);
    __syncthreads();
    for (int k = cbeg + t; k < cend; k += 256) {
        int w = widx[k];
        int pos = atomicAdd(&lb[w], 1);
        unsigned long long pk = (unsigned long long)(unsigned)u[k] |
                                ((unsigned long long)(unsigned)v[k] << 32);
        __hip_atomic_store(&perm64[pos], pk, __ATOMIC_RELAXED,
                           __HIP_MEMORY_SCOPE_AGENT);
    }
    grid.sync();

    // ---- phase 2: bucketed mm (proven round-4 inner loop) ------------------
    {
        const uint2* perm = (const uint2*)perm64;
        int NS = G >> 8;                 // slices per bucket
        int w = b & (NW_MAX - 1);
        int s = b >> 8;
        int bb = sbase[w];
        int cnt = sbase[w + 1] - bb;
        int begin = bb + cnt / NS * s + min(s, cnt % NS);
        int end   = begin + cnt / NS + (s < (cnt % NS) ? 1 : 0);
        int o = t & 15;
        int g = t >> 4;

        const float* Wr = W + ((size_t)w << 8) + (o << 4);
        float4 w0 = *(const float4*)(Wr + 0);
        float4 w1 = *(const float4*)(Wr + 4);
        float4 w2 = *(const float4*)(Wr + 8);
        float4 w3 = *(const float4*)(Wr + 12);

        for (int j = begin + g; j < end; j += 16) {
            uint2 pe = perm[j];
            float xv = x[((size_t)pe.x << 4) + o];
            float a = 0.0f;
            a += w0.x * __shfl(xv,  0, 16);
            a += w0.y * __shfl(xv,  1, 16);
            a += w0.z * __shfl(xv,  2, 16);
            a += w0.w * __shfl(xv,  3, 16);
            a += w1.x * __shfl(xv,  4, 16);
            a += w1.y * __shfl(xv,  5, 16);
            a += w1.z * __shfl(xv,  6, 16);
            a += w1.w * __shfl(xv,  7, 16);
            a += w2.x * __shfl(xv,  8, 16);
            a += w2.y * __shfl(xv,  9, 16);
            a += w2.z * __shfl(xv, 10, 16);
            a += w2.w * __shfl(xv, 11, 16);
            a += w3.x * __shfl(xv, 12, 16);
            a += w3.y * __shfl(xv, 13, 16);
            a += w3.z * __shfl(xv, 14, 16);
            a += w3.w * __shfl(xv, 15, 16);
            atomicAdd(out + ((size_t)pe.y << 4) + o, a);
        }
    }
    grid.sync();

    // ---- phase 3: fused ReLU (scoped loads bypass stale clean lines) -------
    for (int i = b * 256 + t; i < ntot; i += G * 256) {
        float val = __hip_atomic_load(&out[i], __ATOMIC_RELAXED,
                                      __HIP_MEMORY_SCOPE_AGENT);
        out[i] = fmaxf(val, 0.0f);
    }
}

// ===========================================================================
// Fallback 1: proven round-4 multi-kernel pipeline (199 us).
// ===========================================================================
__global__ __launch_bounds__(256) void hist_kernel(
    const int* __restrict__ widx, int* __restrict__ counts, int BP, int E,
    float4* __restrict__ outz, int n4) {
    __shared__ int h[NW_MAX];
    int t = threadIdx.x;
    for (int i = blockIdx.x * 256 + t; i < n4; i += gridDim.x * 256)
        outz[i] = make_float4(0.f, 0.f, 0.f, 0.f);
    h[t] = 0;
    __syncthreads();
    int base = blockIdx.x * CHUNK4;
    int lim = E - base; if (lim > CHUNK4) lim = CHUNK4;
    for (int k = t; k < lim; k += 256)
        atomicAdd(&h[widx[base + k]], 1);
    __syncthreads();
    counts[t * BP + blockIdx.x] = h[t];
}

__global__ __launch_bounds__(256) void rowscan_kernel(
    int* __restrict__ counts, int* __restrict__ rowTotal, int BP, int B) {
    int t = threadIdx.x;
    int w = blockIdx.x * 4 + (t >> 6);
    int lane = t & 63;
    int run = 0;
    for (int b0 = 0; b0 < BP; b0 += 64) {
        int b = b0 + lane;
        int val = (b < B) ? counts[w * BP + b] : 0;
        int incl = val;
        #pragma unroll
        for (int d = 1; d < 64; d <<= 1) {
            int tmp = __shfl_up(incl, d, 64);
            if (lane >= d) incl += tmp;
        }
        if (b < B) counts[w * BP + b] = run + incl - val;
        run += __shfl(incl, 63, 64);
    }
    if (lane == 0) rowTotal[w] = run;
}

__global__ __launch_bounds__(256) void basescan_kernel(
    const int* __restrict__ rowTotal, int* __restrict__ bucketBase) {
    __shared__ int s[NW_MAX];
    int t = threadIdx.x;
    int mine = rowTotal[t];
    s[t] = mine;
    __syncthreads();
    for (int d = 1; d < NW_MAX; d <<= 1) {
        int val = s[t];
        int add = (t >= d) ? s[t - d] : 0;
        __syncthreads();
        s[t] = val + add;
        __syncthreads();
    }
    bucketBase[t] = s[t] - mine;
    if (t == NW_MAX - 1) bucketBase[NW_MAX] = s[t];
}

__global__ __launch_bounds__(256) void scatter_kernel(
    const int* __restrict__ u, const int* __restrict__ v,
    const int* __restrict__ widx, const int* __restrict__ counts,
    const int* __restrict__ bucketBase, uint2* __restrict__ perm,
    int BP, int E) {
    __shared__ int cur[NW_MAX];
    int t = threadIdx.x;
    int b = blockIdx.x;
    cur[t] = bucketBase[t] + counts[t * BP + b];
    __syncthreads();
    int base = b * CHUNK4;
    int lim = E - base; if (lim > CHUNK4) lim = CHUNK4;
    for (int k = t; k < lim; k += 256) {
        int e = base + k;
        int w = widx[e];
        int pos = atomicAdd(&cur[w], 1);
        perm[pos] = make_uint2((unsigned)u[e], (unsigned)v[e]);
    }
}

__global__ __launch_bounds__(256) void bucket_mm_kernel(
    const float* __restrict__ x, const float* __restrict__ W,
    const int* __restrict__ bucketBase, const uint2* __restrict__ perm,
    float* __restrict__ out) {
    int w = blockIdx.x >> 3;
    int s = blockIdx.x & 7;
    int base = bucketBase[w];
    int cnt  = bucketBase[w + 1] - base;
    int begin = base + (cnt * s) / 8;
    int end   = base + (cnt * (s + 1)) / 8;
    int o = threadIdx.x & 15;
    int g = threadIdx.x >> 4;

    const float* Wr = W + ((size_t)w << 8) + (o << 4);
    float4 w0 = *(const float4*)(Wr + 0);
    float4 w1 = *(const float4*)(Wr + 4);
    float4 w2 = *(const float4*)(Wr + 8);
    float4 w3 = *(const float4*)(Wr + 12);

    for (int j = begin + g; j < end; j += 16) {
        uint2 pe = perm[j];
        float xv = x[((size_t)pe.x << 4) + o];
        float a = 0.0f;
        a += w0.x * __shfl(xv,  0, 16);
        a += w0.y * __shfl(xv,  1, 16);
        a += w0.z * __shfl(xv,  2, 16);
        a += w0.w * __shfl(xv,  3, 16);
        a += w1.x * __shfl(xv,  4, 16);
        a += w1.y * __shfl(xv,  5, 16);
        a += w1.z * __shfl(xv,  6, 16);
        a += w1.w * __shfl(xv,  7, 16);
        a += w2.x * __shfl(xv,  8, 16);
        a += w2.y * __shfl(xv,  9, 16);
        a += w2.z * __shfl(xv, 10, 16);
        a += w2.w * __shfl(xv, 11, 16);
        a += w3.x * __shfl(xv, 12, 16);
        a += w3.y * __shfl(xv, 13, 16);
        a += w3.z * __shfl(xv, 14, 16);
        a += w3.w * __shfl(xv, 15, 16);
        atomicAdd(out + ((size_t)pe.y << 4) + o, a);
    }
}

__global__ __launch_bounds__(256) void relu_kernel(float* __restrict__ out, int n4) {
    int i = blockIdx.x * 256 + threadIdx.x;
    if (i >= n4) return;
    float4* p = (float4*)out + i;
    float4 val = *p;
    val.x = fmaxf(val.x, 0.0f);
    val.y = fmaxf(val.y, 0.0f);
    val.z = fmaxf(val.z, 0.0f);
    val.w = fmaxf(val.w, 0.0f);
    *p = val;
}

// Fallback 2: original edge-parallel atomic path.
__global__ __launch_bounds__(256) void edge_scatter_kernel(
    const float* __restrict__ x, const float* __restrict__ W,
    const int* __restrict__ u, const int* __restrict__ v,
    const int* __restrict__ widx, float* __restrict__ out, int E) {
    int tid = blockIdx.x * 256 + threadIdx.x;
    int e = tid >> 4;
    int o = tid & 15;
    if (e >= E) return;
    int w = widx[e], uu = u[e], vv = v[e];
    const float* Wr = W + (size_t)w * (D * D) + (size_t)o * D;
    float4 w0 = *(const float4*)(Wr + 0);
    float4 w1 = *(const float4*)(Wr + 4);
    float4 w2 = *(const float4*)(Wr + 8);
    float4 w3 = *(const float4*)(Wr + 12);
    float xv = x[(size_t)uu * D + o];
    float acc = 0.0f;
    acc += w0.x * __shfl(xv,  0, 16);
    acc += w0.y * __shfl(xv,  1, 16);
    acc += w0.z * __shfl(xv,  2, 16);
    acc += w0.w * __shfl(xv,  3, 16);
    acc += w1.x * __shfl(xv,  4, 16);
    acc += w1.y * __shfl(xv,  5, 16);
    acc += w1.z * __shfl(xv,  6, 16);
    acc += w1.w * __shfl(xv,  7, 16);
    acc += w2.x * __shfl(xv,  8, 16);
    acc += w2.y * __shfl(xv,  9, 16);
    acc += w2.z * __shfl(xv, 10, 16);
    acc += w2.w * __shfl(xv, 11, 16);
    acc += w3.x * __shfl(xv, 12, 16);
    acc += w3.y * __shfl(xv, 13, 16);
    acc += w3.z * __shfl(xv, 14, 16);
    acc += w3.w * __shfl(xv, 15, 16);
    atomicAdd(out + (size_t)vv * D + o, acc);
}

extern "C" void kernel_launch(void* const* d_in, const int* in_sizes, int n_in,
                              void* d_out, int out_size, void* d_ws, size_t ws_size,
                              hipStream_t stream) {
    const float* x    = (const float*)d_in[0];
    const float* W    = (const float*)d_in[1];
    const int*   u    = (const int*)d_in[2];
    const int*   v    = (const int*)d_in[3];
    const int*   widx = (const int*)d_in[4];
    float* out = (float*)d_out;

    int E  = in_sizes[2];
    int NW = in_sizes[1] / (D * D);
    int ntot = out_size;            // total floats in out
    int n4 = out_size / 4;

    // Cooperative grid size: multiple of 256 (phase-2 bucket mapping),
    // capped by occupancy so all blocks are co-resident.
    static int s_grid = -1;
    if (s_grid < 0) {
        hipDeviceProp_t prop;
        int dev = 0;
        int maxB = 0;
        hipError_t e0 = hipGetDevice(&dev);
        hipError_t e1 = hipGetDeviceProperties(&prop, dev);
        hipError_t e2 = hipOccupancyMaxActiveBlocksPerMultiprocessor(
            &maxB, fused_kernel, 256, 0);
        if (e0 == hipSuccess && e1 == hipSuccess && e2 == hipSuccess) {
            long long cap = (long long)maxB * prop.multiProcessorCount;
            int ns = (int)(cap / 256);
            if (ns > 3) ns = 3;
            s_grid = (ns >= 1) ? ns * NW_MAX : 0;
        } else {
            s_grid = 0;
        }
    }

    // Fused-path workspace: bucketTotal[256] | gcur[256] | perm64[E]
    size_t head = 2048;
    size_t need = head + (size_t)E * 8;

    if (NW <= NW_MAX && s_grid > 0 && ws_size >= need) {
        int* bucketTotal = (int*)d_ws;
        int* gcur        = (int*)((char*)d_ws + 1024);
        unsigned long long* perm64 = (unsigned long long*)((char*)d_ws + head);

        hipError_t em = hipMemsetAsync(d_ws, 0, head, stream);

        void* args[] = {(void*)&x, (void*)&W, (void*)&u, (void*)&v,
                        (void*)&widx, (void*)&out, (void*)&bucketTotal,
                        (void*)&gcur, (void*)&perm64, (void*)&E, (void*)&ntot};
        hipError_t err = hipLaunchCooperativeKernel(
            fused_kernel, dim3(s_grid), dim3(256), args, 0, stream);
        if (em == hipSuccess && err == hipSuccess) return;
        s_grid = 0;  // don't retry the coop path on later calls
    }

    // Fallback 1: round-4 multi-kernel pipeline.
    int B  = (E + CHUNK4 - 1) / CHUNK4;
    int BP = (B + 63) & ~63;
    size_t counts_b = (size_t)NW_MAX * BP * 4;
    size_t head2 = counts_b + (size_t)NW_MAX * 4 + 260 * 4;
    size_t need2 = head2 + (size_t)E * 8;

    if (NW <= NW_MAX && ws_size >= need2) {
        int* counts     = (int*)d_ws;
        int* rowTotal   = (int*)((char*)d_ws + counts_b);
        int* bucketBase = (int*)((char*)d_ws + counts_b + (size_t)NW_MAX * 4);
        uint2* perm     = (uint2*)((char*)d_ws + head2);

        hist_kernel<<<B, 256, 0, stream>>>(widx, counts, BP, E, (float4*)out, n4);
        rowscan_kernel<<<64, 256, 0, stream>>>(counts, rowTotal, BP, B);
        basescan_kernel<<<1, 256, 0, stream>>>(rowTotal, bucketBase);
        scatter_kernel<<<B, 256, 0, stream>>>(u, v, widx, counts, bucketBase, perm, BP, E);
        bucket_mm_kernel<<<NW_MAX * 8, 256, 0, stream>>>(x, W, bucketBase, perm, out);
        int rblocks = (n4 + 255) / 256;
        relu_kernel<<<rblocks, 256, 0, stream>>>(out, n4);
    } else {
        // Fallback 2: edge-parallel atomics.
        hipError_t em2 = hipMemsetAsync(d_out, 0, (size_t)out_size * sizeof(float), stream);
        (void)em2;
        int total_threads = E * 16;
        int blocks = (total_threads + 255) / 256;
        edge_scatter_kernel<<<blocks, 256, 0, stream>>>(x, W, u, v, widx, out, E);
        int rblocks = (n4 + 255) / 256;
        relu_kernel<<<rblocks, 256, 0, stream>>>(out, n4);
    }
}